// Round 1
// baseline (266.549 us; speedup 1.0000x reference)
//
#include <hip/hip_runtime.h>
#include <math.h>

// Quadrotor dynamics: per-batch-element, fully independent -> 1 thread/element.
// state row = 32 floats = exactly one 128B cache line, so per-lane float4
// loads/stores fully consume their lines (no DRAM over-fetch).

#define MASSF      1.5f
#define INV_MASSF  (1.0f / 1.5f)
#define GRAVF      9.81f
#define KDF        0.1f
#define KHF        0.01f
#define JXF        0.0211f
#define JYF        0.0219f
#define JZF        0.0366f
#define JIXF       (1.0f / 0.0211f)
#define JIYF       (1.0f / 0.0219f)
#define JIZF       (1.0f / 0.0366f)
#define PI_2F      1.57079632679489661923f

__device__ __forceinline__ void rb_deriv(const float x[13], const float fm[6], float k[13]) {
    // x = [pos(3), v(3), q(4), w(3)], fm = [f_i(3), m_b(3)]
    k[0] = x[3]; k[1] = x[4]; k[2] = x[5];
    k[3] = fm[0] * INV_MASSF;
    k[4] = fm[1] * INV_MASSF;
    k[5] = fm[2] * INV_MASSF + GRAVF;
    const float ew = x[6], ex = x[7], ey = x[8], ez = x[9];
    const float p = x[10], q = x[11], r = x[12];
    k[6] = 0.5f * (-ex * p - ey * q - ez * r);
    k[7] = 0.5f * ( ew * p + ey * r - ez * q);
    k[8] = 0.5f * ( ew * q - ex * r + ez * p);
    k[9] = 0.5f * ( ew * r + ex * q - ey * p);
    const float Jwx = JXF * p, Jwy = JYF * q, Jwz = JZF * r;
    const float c0 = q * Jwz - r * Jwy;
    const float c1 = r * Jwx - p * Jwz;
    const float c2 = p * Jwy - q * Jwx;
    k[10] = (fm[3] - c0) * JIXF;
    k[11] = (fm[4] - c1) * JIYF;
    k[12] = (fm[5] - c2) * JIZF;
}

__global__ __launch_bounds__(256) void qd_dynamics_kernel(
    const float* __restrict__ state,
    const float* __restrict__ delta,
    const float* __restrict__ G1,
    const float* __restrict__ dtp,
    float* __restrict__ out,
    int B)
{
    const int b = blockIdx.x * blockDim.x + threadIdx.x;
    if (b >= B) return;

    // ---- load state row (8 x float4, 128B line per element) ----
    float s[32];
    const float4* sp = (const float4*)(state + (size_t)b * 32);
    float4* sl = (float4*)s;
    #pragma unroll
    for (int i = 0; i < 8; ++i) sl[i] = sp[i];

    const float4 dl = ((const float4*)delta)[b];
    const float dt = dtp[0];

    // G1 row-major 4x4 (uniform across threads; L1 broadcast)
    float g[16];
    const float4* gp = (const float4*)G1;
    float4* gl = (float4*)g;
    #pragma unroll
    for (int i = 0; i < 4; ++i) gl[i] = gp[i];

    // ---- motor thrust/moments: tt = G1 @ clip(delta)^2 ----
    float d0 = fminf(fmaxf(dl.x, 0.0f), 1000.0f);
    float d1 = fminf(fmaxf(dl.y, 0.0f), 1000.0f);
    float d2 = fminf(fmaxf(dl.z, 0.0f), 1000.0f);
    float d3 = fminf(fmaxf(dl.w, 0.0f), 1000.0f);
    d0 *= d0; d1 *= d1; d2 *= d2; d3 *= d3;
    const float T  = g[0]  * d0 + g[1]  * d1 + g[2]  * d2 + g[3]  * d3;
    const float Mx = g[4]  * d0 + g[5]  * d1 + g[6]  * d2 + g[7]  * d3;
    const float My = g[8]  * d0 + g[9]  * d1 + g[10] * d2 + g[11] * d3;
    const float Mz = g[12] * d0 + g[13] * d1 + g[14] * d2 + g[15] * d3;

    // ---- rotation matrix from ORIGINAL quaternion s[9..12] ----
    const float ew = s[9], ex = s[10], ey = s[11], ez = s[12];
    const float r00 = ew*ew + ex*ex - ey*ey - ez*ez;
    const float r01 = 2.0f * (ex*ey - ew*ez);
    const float r02 = 2.0f * (ex*ez + ew*ey);
    const float r10 = 2.0f * (ex*ey + ew*ez);
    const float r11 = ew*ew - ex*ex + ey*ey - ez*ez;
    const float r12 = 2.0f * (ey*ez - ew*ex);
    const float r20 = 2.0f * (ex*ez - ew*ey);
    const float r21 = 2.0f * (ey*ez + ew*ex);
    const float r22 = ew*ew - ex*ex - ey*ey + ez*ez;

    // ---- wind in body frame: V_wind_b = R^T @ wind ----
    const float wx = s[28], wy = s[29], wz = s[30];
    const float vwb0 = r00 * wx + r10 * wy + r20 * wz;
    const float vwb1 = r01 * wx + r11 * wy + r21 * wz;
    const float vwb2 = r02 * wx + r12 * wy + r22 * wz;

    const float u_r = s[16] - vwb0;
    const float v_r = s[17] - vwb1;
    const float w_r = s[18] - vwb2;
    const float Va = sqrtf(u_r * u_r + v_r * v_r + w_r * w_r);
    const float alpha = (u_r == 0.0f) ? PI_2F : atan2f(w_r, u_r);
    const float beta = (Va == 0.0f)
        ? 0.0f
        : asinf(fminf(fmaxf(v_r / Va, -1.0f), 1.0f));

    // ---- body forces -> inertial ----
    const float fx = -KDF * u_r;
    const float fy = -KDF * v_r;
    const float fz = -T - KDF * w_r + KHF * (u_r * u_r + v_r * v_r);
    float fm[6];
    fm[0] = r00 * fx + r01 * fy + r02 * fz;
    fm[1] = r10 * fx + r11 * fy + r12 * fz;
    fm[2] = r20 * fx + r21 * fy + r22 * fz;
    fm[3] = Mx; fm[4] = My; fm[5] = Mz;

    // ---- RK4 on [pos, v, q, w] ----
    float x0[13];
    x0[0] = s[3];  x0[1] = s[4];  x0[2] = s[5];
    x0[3] = s[13]; x0[4] = s[14]; x0[5] = s[15];
    x0[6] = s[9];  x0[7] = s[10]; x0[8] = s[11]; x0[9] = s[12];
    x0[10] = s[19]; x0[11] = s[20]; x0[12] = s[21];

    float k1[13], k2[13], k3[13], k4[13], xt[13], xn[13];
    rb_deriv(x0, fm, k1);
    #pragma unroll
    for (int i = 0; i < 13; ++i) xt[i] = x0[i] + 0.5f * dt * k1[i];
    rb_deriv(xt, fm, k2);
    #pragma unroll
    for (int i = 0; i < 13; ++i) xt[i] = x0[i] + 0.5f * dt * k2[i];
    rb_deriv(xt, fm, k3);
    #pragma unroll
    for (int i = 0; i < 13; ++i) xt[i] = x0[i] + dt * k3[i];
    rb_deriv(xt, fm, k4);
    const float dt6 = dt / 6.0f;
    #pragma unroll
    for (int i = 0; i < 13; ++i)
        xn[i] = x0[i] + dt6 * (k1[i] + 2.0f * k2[i] + 2.0f * k3[i] + k4[i]);

    // ---- normalize new quaternion ----
    float qw = xn[6], qx = xn[7], qy = xn[8], qz = xn[9];
    const float qn = sqrtf(qw * qw + qx * qx + qy * qy + qz * qz);
    qw /= qn; qx /= qn; qy /= qn; qz /= qn;

    // ---- euler angles from NEW quaternion ----
    const float phi = atan2f(2.0f * (qw * qx + qy * qz),
                             qw * qw + qz * qz - qx * qx - qy * qy);
    const float theta = asinf(fminf(fmaxf(2.0f * (qw * qy - qx * qz), -1.0f), 1.0f));
    const float psi = atan2f(2.0f * (qw * qz + qx * qy),
                             qw * qw + qx * qx - qy * qy - qz * qz);

    // ---- ground speed from ORIGINAL R and body velocity s[16..18] ----
    const float p0 = r00 * s[16] + r01 * s[17] + r02 * s[18];
    const float p1 = r10 * s[16] + r11 * s[17] + r12 * s[18];
    const float p2 = r20 * s[16] + r21 * s[17] + r22 * s[18];
    const float Vg = sqrtf(p0 * p0 + p1 * p1 + p2 * p2);
    const float vg_safe = (Vg == 0.0f) ? 1.0f : Vg;
    const float gamma = asinf(fminf(fmaxf(p2 / vg_safe, -1.0f), 1.0f));
    const float chi = atan2f(p1, p0);

    // ---- assemble output row ----
    float o[32];
    o[0] = s[0]; o[1] = s[1]; o[2] = s[2];
    o[3] = xn[0]; o[4] = xn[1]; o[5] = xn[2];
    o[6] = phi; o[7] = theta; o[8] = psi;
    o[9] = qw; o[10] = qx; o[11] = qy; o[12] = qz;
    o[13] = xn[3]; o[14] = xn[4]; o[15] = xn[5];
    o[16] = s[16]; o[17] = s[17]; o[18] = s[18];
    o[19] = xn[10]; o[20] = xn[11]; o[21] = xn[12];
    o[22] = Va; o[23] = Vg;
    o[24] = alpha; o[25] = beta;
    o[26] = gamma; o[27] = chi;
    o[28] = s[28]; o[29] = s[29]; o[30] = s[30]; o[31] = s[31];

    float4* op = (float4*)(out + (size_t)b * 32);
    const float4* ol = (const float4*)o;
    #pragma unroll
    for (int i = 0; i < 8; ++i) op[i] = ol[i];
}

extern "C" void kernel_launch(void* const* d_in, const int* in_sizes, int n_in,
                              void* d_out, int out_size, void* d_ws, size_t ws_size,
                              hipStream_t stream) {
    const float* state = (const float*)d_in[0];
    const float* delta = (const float*)d_in[1];
    const float* G1    = (const float*)d_in[2];
    const float* dtp   = (const float*)d_in[3];
    float* out = (float*)d_out;
    const int B = in_sizes[0] / 32;
    const int block = 256;
    const int grid = (B + block - 1) / block;
    hipLaunchKernelGGL(qd_dynamics_kernel, dim3(grid), dim3(block), 0, stream,
                       state, delta, G1, dtp, out, B);
}

// Round 2
// 247.813 us; speedup vs baseline: 1.0756x; 1.0756x over previous
//
#include <hip/hip_runtime.h>
#include <math.h>

// Quadrotor dynamics, B=2^20 independent elements, 32-float AoS rows.
// Round 1 showed the naive 1-thread/row pattern is VMEM-transaction-bound
// (each wave-load touches 64 cache lines). Fix: coalesced global <-> LDS
// staging in both directions; each thread then reads/writes its own row
// from/to LDS (padded stride 36 floats = 144B, 16B-aligned, even bank use).

#define INV_MASSF  (1.0f / 1.5f)
#define GRAVF      9.81f
#define KDF        0.1f
#define KHF        0.01f
#define JXF        0.0211f
#define JYF        0.0219f
#define JZF        0.0366f
#define JIXF       (1.0f / 0.0211f)
#define JIYF       (1.0f / 0.0219f)
#define JIZF       (1.0f / 0.0366f)
#define PI_2F      1.57079632679489661923f

#define ROWS    256          // threads (rows) per block
#define STRIDE  36           // padded LDS row stride in floats (36*4=144B, %16==0)

__device__ __forceinline__ void rb_deriv(const float x[13], const float fm[6], float k[13]) {
    k[0] = x[3]; k[1] = x[4]; k[2] = x[5];
    k[3] = fm[0] * INV_MASSF;
    k[4] = fm[1] * INV_MASSF;
    k[5] = fm[2] * INV_MASSF + GRAVF;
    const float ew = x[6], ex = x[7], ey = x[8], ez = x[9];
    const float p = x[10], q = x[11], r = x[12];
    k[6] = 0.5f * (-ex * p - ey * q - ez * r);
    k[7] = 0.5f * ( ew * p + ey * r - ez * q);
    k[8] = 0.5f * ( ew * q - ex * r + ez * p);
    k[9] = 0.5f * ( ew * r + ex * q - ey * p);
    const float Jwx = JXF * p, Jwy = JYF * q, Jwz = JZF * r;
    const float c0 = q * Jwz - r * Jwy;
    const float c1 = r * Jwx - p * Jwz;
    const float c2 = p * Jwy - q * Jwx;
    k[10] = (fm[3] - c0) * JIXF;
    k[11] = (fm[4] - c1) * JIYF;
    k[12] = (fm[5] - c2) * JIZF;
}

__device__ __forceinline__ void qd_compute(const float s[32], float4 dl,
                                           const float g[16], float dt,
                                           float o[32]) {
    // ---- motor thrust/moments: tt = G1 @ clip(delta)^2 ----
    float d0 = fminf(fmaxf(dl.x, 0.0f), 1000.0f);
    float d1 = fminf(fmaxf(dl.y, 0.0f), 1000.0f);
    float d2 = fminf(fmaxf(dl.z, 0.0f), 1000.0f);
    float d3 = fminf(fmaxf(dl.w, 0.0f), 1000.0f);
    d0 *= d0; d1 *= d1; d2 *= d2; d3 *= d3;
    const float T  = g[0]  * d0 + g[1]  * d1 + g[2]  * d2 + g[3]  * d3;
    const float Mx = g[4]  * d0 + g[5]  * d1 + g[6]  * d2 + g[7]  * d3;
    const float My = g[8]  * d0 + g[9]  * d1 + g[10] * d2 + g[11] * d3;
    const float Mz = g[12] * d0 + g[13] * d1 + g[14] * d2 + g[15] * d3;

    // ---- rotation matrix from ORIGINAL quaternion s[9..12] ----
    const float ew = s[9], ex = s[10], ey = s[11], ez = s[12];
    const float r00 = ew*ew + ex*ex - ey*ey - ez*ez;
    const float r01 = 2.0f * (ex*ey - ew*ez);
    const float r02 = 2.0f * (ex*ez + ew*ey);
    const float r10 = 2.0f * (ex*ey + ew*ez);
    const float r11 = ew*ew - ex*ex + ey*ey - ez*ez;
    const float r12 = 2.0f * (ey*ez - ew*ex);
    const float r20 = 2.0f * (ex*ez - ew*ey);
    const float r21 = 2.0f * (ey*ez + ew*ex);
    const float r22 = ew*ew - ex*ex - ey*ey + ez*ez;

    // ---- wind in body frame: V_wind_b = R^T @ wind ----
    const float wx = s[28], wy = s[29], wz = s[30];
    const float vwb0 = r00 * wx + r10 * wy + r20 * wz;
    const float vwb1 = r01 * wx + r11 * wy + r21 * wz;
    const float vwb2 = r02 * wx + r12 * wy + r22 * wz;

    const float u_r = s[16] - vwb0;
    const float v_r = s[17] - vwb1;
    const float w_r = s[18] - vwb2;
    const float Va = sqrtf(u_r * u_r + v_r * v_r + w_r * w_r);
    const float alpha = (u_r == 0.0f) ? PI_2F : atan2f(w_r, u_r);
    const float beta = (Va == 0.0f)
        ? 0.0f
        : asinf(fminf(fmaxf(v_r / Va, -1.0f), 1.0f));

    // ---- body forces -> inertial ----
    const float fx = -KDF * u_r;
    const float fy = -KDF * v_r;
    const float fz = -T - KDF * w_r + KHF * (u_r * u_r + v_r * v_r);
    float fm[6];
    fm[0] = r00 * fx + r01 * fy + r02 * fz;
    fm[1] = r10 * fx + r11 * fy + r12 * fz;
    fm[2] = r20 * fx + r21 * fy + r22 * fz;
    fm[3] = Mx; fm[4] = My; fm[5] = Mz;

    // ---- RK4 on [pos, v, q, w] ----
    float x0[13];
    x0[0] = s[3];  x0[1] = s[4];  x0[2] = s[5];
    x0[3] = s[13]; x0[4] = s[14]; x0[5] = s[15];
    x0[6] = s[9];  x0[7] = s[10]; x0[8] = s[11]; x0[9] = s[12];
    x0[10] = s[19]; x0[11] = s[20]; x0[12] = s[21];

    float k1[13], k2[13], k3[13], k4[13], xt[13], xn[13];
    rb_deriv(x0, fm, k1);
    #pragma unroll
    for (int i = 0; i < 13; ++i) xt[i] = x0[i] + 0.5f * dt * k1[i];
    rb_deriv(xt, fm, k2);
    #pragma unroll
    for (int i = 0; i < 13; ++i) xt[i] = x0[i] + 0.5f * dt * k2[i];
    rb_deriv(xt, fm, k3);
    #pragma unroll
    for (int i = 0; i < 13; ++i) xt[i] = x0[i] + dt * k3[i];
    rb_deriv(xt, fm, k4);
    const float dt6 = dt / 6.0f;
    #pragma unroll
    for (int i = 0; i < 13; ++i)
        xn[i] = x0[i] + dt6 * (k1[i] + 2.0f * k2[i] + 2.0f * k3[i] + k4[i]);

    // ---- normalize new quaternion ----
    float qw = xn[6], qx = xn[7], qy = xn[8], qz = xn[9];
    const float qn = sqrtf(qw * qw + qx * qx + qy * qy + qz * qz);
    qw /= qn; qx /= qn; qy /= qn; qz /= qn;

    // ---- euler angles from NEW quaternion ----
    const float phi = atan2f(2.0f * (qw * qx + qy * qz),
                             qw * qw + qz * qz - qx * qx - qy * qy);
    const float theta = asinf(fminf(fmaxf(2.0f * (qw * qy - qx * qz), -1.0f), 1.0f));
    const float psi = atan2f(2.0f * (qw * qz + qx * qy),
                             qw * qw + qx * qx - qy * qy - qz * qz);

    // ---- ground speed from ORIGINAL R and body velocity s[16..18] ----
    const float p0 = r00 * s[16] + r01 * s[17] + r02 * s[18];
    const float p1 = r10 * s[16] + r11 * s[17] + r12 * s[18];
    const float p2 = r20 * s[16] + r21 * s[17] + r22 * s[18];
    const float Vg = sqrtf(p0 * p0 + p1 * p1 + p2 * p2);
    const float vg_safe = (Vg == 0.0f) ? 1.0f : Vg;
    const float gamma = asinf(fminf(fmaxf(p2 / vg_safe, -1.0f), 1.0f));
    const float chi = atan2f(p1, p0);

    // ---- assemble output row ----
    o[0] = s[0]; o[1] = s[1]; o[2] = s[2];
    o[3] = xn[0]; o[4] = xn[1]; o[5] = xn[2];
    o[6] = phi; o[7] = theta; o[8] = psi;
    o[9] = qw; o[10] = qx; o[11] = qy; o[12] = qz;
    o[13] = xn[3]; o[14] = xn[4]; o[15] = xn[5];
    o[16] = s[16]; o[17] = s[17]; o[18] = s[18];
    o[19] = xn[10]; o[20] = xn[11]; o[21] = xn[12];
    o[22] = Va; o[23] = Vg;
    o[24] = alpha; o[25] = beta;
    o[26] = gamma; o[27] = chi;
    o[28] = s[28]; o[29] = s[29]; o[30] = s[30]; o[31] = s[31];
}

__global__ __launch_bounds__(ROWS) void qd_dynamics_kernel(
    const float* __restrict__ state,
    const float* __restrict__ delta,
    const float* __restrict__ G1,
    const float* __restrict__ dtp,
    float* __restrict__ out,
    int B)
{
    __shared__ float lds[ROWS * STRIDE];   // 36 KB

    const int tid = threadIdx.x;
    const int row0 = blockIdx.x * ROWS;    // first element row of this block
    const bool full = (row0 + ROWS) <= B;

    const float dt = dtp[0];
    float g[16];
    {
        const float4* gp = (const float4*)G1;
        float4* gl = (float4*)g;
        #pragma unroll
        for (int i = 0; i < 4; ++i) gl[i] = gp[i];
    }

    float s[32], o[32];
    float4 dl;

    if (full) {
        // ---- coalesced stage-in: lane i loads consecutive float4s ----
        const float4* gp4 = (const float4*)(state + (size_t)row0 * 32);
        #pragma unroll
        for (int i = 0; i < 8; ++i) {
            const int f4 = i * ROWS + tid;       // float4 index in tile
            const int f  = f4 * 4;               // float index in tile
            const int r  = f >> 5;               // row  (f/32)
            const int c  = f & 31;               // col
            *(float4*)&lds[r * STRIDE + c] = gp4[f4];
        }
        __syncthreads();
        #pragma unroll
        for (int i = 0; i < 8; ++i)
            ((float4*)s)[i] = *(const float4*)&lds[tid * STRIDE + i * 4];
        dl = ((const float4*)delta)[row0 + tid];
    } else {
        const int b = row0 + tid;
        const int bb = (b < B) ? b : (B - 1);
        const float4* sp = (const float4*)(state + (size_t)bb * 32);
        #pragma unroll
        for (int i = 0; i < 8; ++i) ((float4*)s)[i] = sp[i];
        dl = ((const float4*)delta)[bb];
        __syncthreads();  // keep barrier count uniform across block
    }

    qd_compute(s, dl, g, dt, o);

    if (full) {
        // thread t owns LDS row t in both phases -> no barrier needed here
        #pragma unroll
        for (int i = 0; i < 8; ++i)
            *(float4*)&lds[tid * STRIDE + i * 4] = ((const float4*)o)[i];
        __syncthreads();
        // ---- coalesced stage-out ----
        float4* op4 = (float4*)(out + (size_t)row0 * 32);
        #pragma unroll
        for (int i = 0; i < 8; ++i) {
            const int f4 = i * ROWS + tid;
            const int f  = f4 * 4;
            const int r  = f >> 5;
            const int c  = f & 31;
            op4[f4] = *(const float4*)&lds[r * STRIDE + c];
        }
    } else {
        __syncthreads();
        const int b = row0 + tid;
        if (b < B) {
            float4* op = (float4*)(out + (size_t)b * 32);
            #pragma unroll
            for (int i = 0; i < 8; ++i) op[i] = ((const float4*)o)[i];
        }
    }
}

extern "C" void kernel_launch(void* const* d_in, const int* in_sizes, int n_in,
                              void* d_out, int out_size, void* d_ws, size_t ws_size,
                              hipStream_t stream) {
    const float* state = (const float*)d_in[0];
    const float* delta = (const float*)d_in[1];
    const float* G1    = (const float*)d_in[2];
    const float* dtp   = (const float*)d_in[3];
    float* out = (float*)d_out;
    const int B = in_sizes[0] / 32;
    const int grid = (B + ROWS - 1) / ROWS;
    hipLaunchKernelGGL(qd_dynamics_kernel, dim3(grid), dim3(ROWS), 0, stream,
                       state, delta, G1, dtp, out, B);
}